// Round 11
// baseline (78.205 us; speedup 1.0000x reference)
//
#include <hip/hip_runtime.h>

typedef __attribute__((ext_vector_type(4))) float f32x4;
typedef __attribute__((ext_vector_type(8))) short bf16x8;

__device__ __forceinline__ short bf16_rne(float f) {
    unsigned int u = __float_as_uint(f);
    u += 0x7FFFu + ((u >> 16) & 1u);
    return (short)(u >> 16);
}

// G=16, in_g=out_g=64. rows-per-group = 32768, total rows = 524288.
// Row r: 64 contiguous floats of x; group g = r>>15.
// out[(g*64+o)*32768 + (r & 32767)].
// PERSISTENT wave: 128 consecutive rows = 2 chunks of 64 rows (4 tiles each),
// one preamble per wave. 4096 waves = 1024 blocks x 4; 256 waves per group.
// NUMERICS: R1's validated path (absmax 0.031): A = bf16(xhat*gamma+beta),
// B = bf16(W), bias in fp32 epilogue.
// STORES (R10 verified): defer all 4 tiles of a chunk in regs, then per
// channel store its FULL contiguous 256 B in 4 back-to-back nt stores.
// This cut WRITE 192->150 MB (ideal 134). 64 channels stride 2^17 B -> same
// L2 set; partial 256B granules must be completed before sister-channel
// stores evict them. Cross-chunk prefetch: chunk c+1 tile-0 loads issue
// BEFORE chunk c's store burst (vmcnt FIFO -> burst doesn't block them).

__global__ __launch_bounds__(256, 3)
void gln_mfma_kernel(const float* __restrict__ x,
                     const float* __restrict__ gamma,
                     const float* __restrict__ beta,
                     const float* __restrict__ W,
                     const float* __restrict__ bias,
                     float* __restrict__ out)
{
    const int tid  = threadIdx.x;
    const int lane = tid & 63;
    const int w    = blockIdx.x * 4 + (tid >> 6);   // 0..4095
    const int g    = w >> 8;                         // 16 groups, 256 waves each
    const int rrb  = (w & 255) << 7;                 // 128-row base in group

    const int l15 = lane & 15;
    const int l4  = lane >> 4;      // 0..3
    const int ks  = l4 * 8;         // k-slice base within a 32-wide K chunk

    // ---- B fragments: lane elem j = W[g][ot*16+l15][kc*32+ks+j] ----
    bf16x8 bfrag[4][2];
    {
        const float* Wg = W + (size_t)(g * 64) * 64;
        #pragma unroll
        for (int ot = 0; ot < 4; ++ot) {
            const float* wrow = Wg + (size_t)(ot * 16 + l15) * 64;
            #pragma unroll
            for (int kc = 0; kc < 2; ++kc) {
                f32x4 w0 = *(const f32x4*)(wrow + kc * 32 + ks);
                f32x4 w1 = *(const f32x4*)(wrow + kc * 32 + ks + 4);
                bf16x8 f;
                #pragma unroll
                for (int j = 0; j < 4; ++j) { f[j] = bf16_rne(w0[j]); f[j + 4] = bf16_rne(w1[j]); }
                bfrag[ot][kc] = f;
            }
        }
    }

    // ---- gamma/beta for this lane's 16 k positions ----
    float gk[16], bk[16];
    {
        const float* gp = gamma + g * 64;
        const float* bp = beta  + g * 64;
        #pragma unroll
        for (int kc = 0; kc < 2; ++kc) {
            f32x4 g0 = *(const f32x4*)(gp + kc * 32 + ks);
            f32x4 g1 = *(const f32x4*)(gp + kc * 32 + ks + 4);
            f32x4 b0 = *(const f32x4*)(bp + kc * 32 + ks);
            f32x4 b1 = *(const f32x4*)(bp + kc * 32 + ks + 4);
            #pragma unroll
            for (int j = 0; j < 4; ++j) {
                gk[kc * 8 + j] = g0[j]; gk[kc * 8 + 4 + j] = g1[j];
                bk[kc * 8 + j] = b0[j]; bk[kc * 8 + 4 + j] = b1[j];
            }
        }
    }

    float bo[4];
    #pragma unroll
    for (int ot = 0; ot < 4; ++ot) bo[ot] = bias[g * 64 + ot * 16 + l15];

    const float* xg = x   + (size_t)g * 32768 * 64;
    float* outg     = out + (size_t)g * 64 * 32768;

    // ---- persistent loop: 2 chunks of 4 tiles, continuous prefetch ----
    f32x4 buf[2][4];
    {
        const float* rowp = xg + (size_t)(rrb + l15) * 64;
        buf[0][0] = *(const f32x4*)(rowp + ks);
        buf[0][1] = *(const f32x4*)(rowp + ks + 4);
        buf[0][2] = *(const f32x4*)(rowp + 32 + ks);
        buf[0][3] = *(const f32x4*)(rowp + 32 + ks + 4);
    }

    #pragma unroll
    for (int c = 0; c < 2; ++c) {
        const int rr0 = rrb + c * 64;
        f32x4 vout[4][4];               // [tile][ot] — stores deferred per chunk

        #pragma unroll
        for (int t = 0; t < 4; ++t) {
            // prefetch: next tile in chunk, or first tile of next chunk.
            // Issued BEFORE this tile's compute and before any store burst.
            const int pf = (t < 3) ? (rr0 + (t + 1) * 16)
                                   : ((c == 0) ? (rrb + 64) : -1);
            if (pf >= 0) {
                const float* rowp = xg + (size_t)(pf + l15) * 64;
                buf[(t + 1) & 1][0] = *(const f32x4*)(rowp + ks);
                buf[(t + 1) & 1][1] = *(const f32x4*)(rowp + ks + 4);
                buf[(t + 1) & 1][2] = *(const f32x4*)(rowp + 32 + ks);
                buf[(t + 1) & 1][3] = *(const f32x4*)(rowp + 32 + ks + 4);
            }

            // LN stats over the row (4 lanes share a row: xor 16, 32)
            float s = 0.f, s2 = 0.f;
            #pragma unroll
            for (int i = 0; i < 4; ++i) {
                #pragma unroll
                for (int j = 0; j < 4; ++j) {
                    float v = buf[t & 1][i][j];
                    s += v; s2 += v * v;
                }
            }
            s  += __shfl_xor(s, 16, 64);  s  += __shfl_xor(s, 32, 64);
            s2 += __shfl_xor(s2, 16, 64); s2 += __shfl_xor(s2, 32, 64);
            const float mu   = s * (1.0f / 64.0f);
            const float var  = s2 * (1.0f / 64.0f) - mu * mu;
            const float rstd = rsqrtf(var + 1e-6f);

            // normalize + affine -> A fragments (bf16)   [R1 numerics]
            bf16x8 a0, a1;
            #pragma unroll
            for (int j = 0; j < 8; ++j) {
                float c1 = rstd * gk[j];
                float v  = buf[t & 1][j >> 2][j & 3] * c1 + (bk[j] - mu * c1);
                a0[j] = bf16_rne(v);
            }
            #pragma unroll
            for (int j = 0; j < 8; ++j) {
                float c1 = rstd * gk[8 + j];
                float v  = buf[t & 1][2 + (j >> 2)][j & 3] * c1 + (bk[8 + j] - mu * c1);
                a1[j] = bf16_rne(v);
            }

            #pragma unroll
            for (int ot = 0; ot < 4; ++ot) {
                f32x4 acc = {0.f, 0.f, 0.f, 0.f};
                acc = __builtin_amdgcn_mfma_f32_16x16x32_bf16(a0, bfrag[ot][0], acc, 0, 0, 0);
                acc = __builtin_amdgcn_mfma_f32_16x16x32_bf16(a1, bfrag[ot][1], acc, 0, 0, 0);
                #pragma unroll
                for (int q = 0; q < 4; ++q) acc[q] += bo[ot];
                vout[t][ot] = acc;
            }
        }

        // ---- chunk epilogue: per channel, FULL 256 B span, 4 adjacent nt stores ----
        #pragma unroll
        for (int ot = 0; ot < 4; ++ot) {
            float* base = outg + (size_t)(ot * 16 + l15) * 32768 + rr0 + l4 * 4;
            #pragma unroll
            for (int t = 0; t < 4; ++t) {
                __builtin_nontemporal_store(vout[t][ot], (f32x4*)(base + t * 16));
            }
        }
    }
}

extern "C" void kernel_launch(void* const* d_in, const int* in_sizes, int n_in,
                              void* d_out, int out_size, void* d_ws, size_t ws_size,
                              hipStream_t stream) {
    const float* x     = (const float*)d_in[0];
    const float* gamma = (const float*)d_in[1];
    const float* beta  = (const float*)d_in[2];
    const float* W     = (const float*)d_in[3];
    const float* b     = (const float*)d_in[4];
    float* out = (float*)d_out;

    dim3 grid(1024), block(256);
    hipLaunchKernelGGL(gln_mfma_kernel, grid, block, 0, stream, x, gamma, beta, W, b, out);
}

// Round 13
// 65.455 us; speedup vs baseline: 1.1948x; 1.1948x over previous
//
#include <hip/hip_runtime.h>

typedef __attribute__((ext_vector_type(4))) float f32x4;
typedef __attribute__((ext_vector_type(8))) short bf16x8;

__device__ __forceinline__ short bf16_rne(float f) {
    unsigned int u = __float_as_uint(f);
    u += 0x7FFFu + ((u >> 16) & 1u);
    return (short)(u >> 16);
}

// G=16, in_g=out_g=64. rows-per-group = 32768, total rows = 524288.
// Row r: 64 contiguous floats of x; group g = r>>15.
// out[(g*64+o)*32768 + (r & 32767)].
// Wave: 64 consecutive rows = 4 tiles of 16 rows. 8192 waves = 2048 blocks x 4.
// NUMERICS: R1's validated path (absmax 0.031): A = bf16(xhat*gamma+beta),
// B = bf16(W), bias in fp32 epilogue.
// STORES (R10-verified local optimum, FROZEN): defer all 4 tiles in vout regs;
// per channel store its FULL contiguous 256 B in 4 back-to-back nt stores at
// wave end. Neighbor 64-row chunks belong to co-resident waves of the same
// block -> adjacent granules complete together. R11 measured: splitting the
// burst per-chunk within a persistent wave re-amplified WRITE 150->210 MB.
// Do NOT restructure the store burst or wave->rows mapping.
// R12 change: 2-deep prefetch (3-buffer rotation) + x loads issued before the
// W/gamma/beta preamble -> 2 outstanding tile-loads hide HBM latency.

__global__ __launch_bounds__(256, 2)
void gln_mfma_kernel(const float* __restrict__ x,
                     const float* __restrict__ gamma,
                     const float* __restrict__ beta,
                     const float* __restrict__ W,
                     const float* __restrict__ bias,
                     float* __restrict__ out)
{
    const int tid  = threadIdx.x;
    const int lane = tid & 63;
    const int w    = blockIdx.x * 4 + (tid >> 6);   // 0..8191
    const int g    = w >> 9;                         // 16 groups, 512 waves each
    const int rr0  = (w & 511) << 6;                 // row-in-group base (64 rows)

    const int l15 = lane & 15;
    const int l4  = lane >> 4;      // 0..3
    const int ks  = l4 * 8;         // k-slice base within a 32-wide K chunk

    const float* xg = x   + (size_t)g * 32768 * 64;
    float* outg     = out + (size_t)g * 64 * 32768;

    // ---- issue x tile-0/1 loads FIRST so HBM latency overlaps the preamble ----
    f32x4 buf[3][4];
    {
        const float* rowp0 = xg + (size_t)(rr0 + l15) * 64;
        buf[0][0] = *(const f32x4*)(rowp0 + ks);
        buf[0][1] = *(const f32x4*)(rowp0 + ks + 4);
        buf[0][2] = *(const f32x4*)(rowp0 + 32 + ks);
        buf[0][3] = *(const f32x4*)(rowp0 + 32 + ks + 4);
        const float* rowp1 = xg + (size_t)(rr0 + 16 + l15) * 64;
        buf[1][0] = *(const f32x4*)(rowp1 + ks);
        buf[1][1] = *(const f32x4*)(rowp1 + ks + 4);
        buf[1][2] = *(const f32x4*)(rowp1 + 32 + ks);
        buf[1][3] = *(const f32x4*)(rowp1 + 32 + ks + 4);
    }

    // ---- B fragments: lane elem j = W[g][ot*16+l15][kc*32+ks+j] ----
    bf16x8 bfrag[4][2];
    {
        const float* Wg = W + (size_t)(g * 64) * 64;
        #pragma unroll
        for (int ot = 0; ot < 4; ++ot) {
            const float* wrow = Wg + (size_t)(ot * 16 + l15) * 64;
            #pragma unroll
            for (int kc = 0; kc < 2; ++kc) {
                f32x4 w0 = *(const f32x4*)(wrow + kc * 32 + ks);
                f32x4 w1 = *(const f32x4*)(wrow + kc * 32 + ks + 4);
                bf16x8 f;
                #pragma unroll
                for (int j = 0; j < 4; ++j) { f[j] = bf16_rne(w0[j]); f[j + 4] = bf16_rne(w1[j]); }
                bfrag[ot][kc] = f;
            }
        }
    }

    // ---- gamma/beta for this lane's 16 k positions ----
    float gk[16], bk[16];
    {
        const float* gp = gamma + g * 64;
        const float* bp = beta  + g * 64;
        #pragma unroll
        for (int kc = 0; kc < 2; ++kc) {
            f32x4 g0 = *(const f32x4*)(gp + kc * 32 + ks);
            f32x4 g1 = *(const f32x4*)(gp + kc * 32 + ks + 4);
            f32x4 b0 = *(const f32x4*)(bp + kc * 32 + ks);
            f32x4 b1 = *(const f32x4*)(bp + kc * 32 + ks + 4);
            #pragma unroll
            for (int j = 0; j < 4; ++j) {
                gk[kc * 8 + j] = g0[j]; gk[kc * 8 + 4 + j] = g1[j];
                bk[kc * 8 + j] = b0[j]; bk[kc * 8 + 4 + j] = b1[j];
            }
        }
    }

    float bo[4];
    #pragma unroll
    for (int ot = 0; ot < 4; ++ot) bo[ot] = bias[g * 64 + ot * 16 + l15];

    f32x4 vout[4][4];                   // [tile][ot] — all stores deferred

    #pragma unroll
    for (int t = 0; t < 4; ++t) {
        // 2-deep prefetch: tile t+2 while computing tile t (t+1 already in flight)
        if (t + 2 < 4) {
            const float* rowp = xg + (size_t)(rr0 + (t + 2) * 16 + l15) * 64;
            buf[(t + 2) % 3][0] = *(const f32x4*)(rowp + ks);
            buf[(t + 2) % 3][1] = *(const f32x4*)(rowp + ks + 4);
            buf[(t + 2) % 3][2] = *(const f32x4*)(rowp + 32 + ks);
            buf[(t + 2) % 3][3] = *(const f32x4*)(rowp + 32 + ks + 4);
        }
        const int tb = t % 3;

        // LN stats over the row (4 lanes share a row: xor 16, 32)
        float s = 0.f, s2 = 0.f;
        #pragma unroll
        for (int i = 0; i < 4; ++i) {
            #pragma unroll
            for (int j = 0; j < 4; ++j) {
                float v = buf[tb][i][j];
                s += v; s2 += v * v;
            }
        }
        s  += __shfl_xor(s, 16, 64);  s  += __shfl_xor(s, 32, 64);
        s2 += __shfl_xor(s2, 16, 64); s2 += __shfl_xor(s2, 32, 64);
        const float mu   = s * (1.0f / 64.0f);
        const float var  = s2 * (1.0f / 64.0f) - mu * mu;
        const float rstd = rsqrtf(var + 1e-6f);

        // normalize + affine -> A fragments (bf16)   [R1 numerics]
        bf16x8 a0, a1;
        #pragma unroll
        for (int j = 0; j < 8; ++j) {
            float c1 = rstd * gk[j];
            float v  = buf[tb][j >> 2][j & 3] * c1 + (bk[j] - mu * c1);
            a0[j] = bf16_rne(v);
        }
        #pragma unroll
        for (int j = 0; j < 8; ++j) {
            float c1 = rstd * gk[8 + j];
            float v  = buf[tb][2 + (j >> 2)][j & 3] * c1 + (bk[8 + j] - mu * c1);
            a1[j] = bf16_rne(v);
        }

        #pragma unroll
        for (int ot = 0; ot < 4; ++ot) {
            f32x4 acc = {0.f, 0.f, 0.f, 0.f};
            acc = __builtin_amdgcn_mfma_f32_16x16x32_bf16(a0, bfrag[ot][0], acc, 0, 0, 0);
            acc = __builtin_amdgcn_mfma_f32_16x16x32_bf16(a1, bfrag[ot][1], acc, 0, 0, 0);
            #pragma unroll
            for (int q = 0; q < 4; ++q) acc[q] += bo[ot];
            vout[t][ot] = acc;
        }
    }

    // ---- epilogue: per channel, its FULL 256 B span in 4 adjacent nt stores ----
    #pragma unroll
    for (int ot = 0; ot < 4; ++ot) {
        float* base = outg + (size_t)(ot * 16 + l15) * 32768 + rr0 + l4 * 4;
        #pragma unroll
        for (int t = 0; t < 4; ++t) {
            __builtin_nontemporal_store(vout[t][ot], (f32x4*)(base + t * 16));
        }
    }
}

extern "C" void kernel_launch(void* const* d_in, const int* in_sizes, int n_in,
                              void* d_out, int out_size, void* d_ws, size_t ws_size,
                              hipStream_t stream) {
    const float* x     = (const float*)d_in[0];
    const float* gamma = (const float*)d_in[1];
    const float* beta  = (const float*)d_in[2];
    const float* W     = (const float*)d_in[3];
    const float* b     = (const float*)d_in[4];
    float* out = (float*)d_out;

    dim3 grid(2048), block(256);
    hipLaunchKernelGGL(gln_mfma_kernel, grid, block, 0, stream, x, gamma, beta, W, b, out);
}

// Round 14
// 65.089 us; speedup vs baseline: 1.2015x; 1.0056x over previous
//
#include <hip/hip_runtime.h>

typedef __attribute__((ext_vector_type(4))) float f32x4;
typedef __attribute__((ext_vector_type(8))) short bf16x8;

__device__ __forceinline__ short bf16_rne(float f) {
    unsigned int u = __float_as_uint(f);
    u += 0x7FFFu + ((u >> 16) & 1u);
    return (short)(u >> 16);
}

// G=16, in_g=out_g=64. rows-per-group = 32768, total rows = 524288.
// Row r: 64 contiguous floats of x; group g = r>>15.
// out[(g*64+o)*32768 + (r & 32767)].
// Wave: 64 consecutive rows = 4 tiles of 16 rows. 8192 waves = 2048 blocks x 4.
// NUMERICS: R1's validated path (absmax 0.031): A = bf16(xhat*gamma+beta),
// B = bf16(W), bias in fp32 epilogue.
// STORES (R10-verified local optimum, FROZEN): defer all 4 tiles in vout regs;
// per channel store its FULL contiguous 256 B in 4 back-to-back nt stores at
// wave end. R11: per-chunk bursts in a persistent wave re-amplify writes.
// LOAD ORDER (R13 lesson): vmcnt is FIFO. Issue W -> gamma/beta/bias -> x.
// Waiting on W/gamma/beta then retires only the older queue entries; the
// younger x loads stay in flight and their HBM latency hides under the
// preamble's cvt/unpack compute. Issuing x FIRST (R13) serialized the
// preamble behind x latency and cost +4us. Do not reorder.

__global__ __launch_bounds__(256, 2)
void gln_mfma_kernel(const float* __restrict__ x,
                     const float* __restrict__ gamma,
                     const float* __restrict__ beta,
                     const float* __restrict__ W,
                     const float* __restrict__ bias,
                     float* __restrict__ out)
{
    const int tid  = threadIdx.x;
    const int lane = tid & 63;
    const int w    = blockIdx.x * 4 + (tid >> 6);   // 0..8191
    const int g    = w >> 9;                         // 16 groups, 512 waves each
    const int rr0  = (w & 511) << 6;                 // row-in-group base (64 rows)

    const int l15 = lane & 15;
    const int l4  = lane >> 4;      // 0..3
    const int ks  = l4 * 8;         // k-slice base within a 32-wide K chunk

    const float* xg = x   + (size_t)g * 32768 * 64;
    float* outg     = out + (size_t)g * 64 * 32768;

    // ---- 1) issue W loads (oldest in vmcnt FIFO) ----
    f32x4 wt0[4][2], wt1[4][2];
    {
        const float* Wg = W + (size_t)(g * 64) * 64;
        #pragma unroll
        for (int ot = 0; ot < 4; ++ot) {
            const float* wrow = Wg + (size_t)(ot * 16 + l15) * 64;
            #pragma unroll
            for (int kc = 0; kc < 2; ++kc) {
                wt0[ot][kc] = *(const f32x4*)(wrow + kc * 32 + ks);
                wt1[ot][kc] = *(const f32x4*)(wrow + kc * 32 + ks + 4);
            }
        }
    }

    // ---- 2) issue gamma/beta/bias loads ----
    f32x4 gt[4], btv[4];
    {
        const float* gp = gamma + g * 64;
        const float* bp = beta  + g * 64;
        #pragma unroll
        for (int kc = 0; kc < 2; ++kc) {
            gt[kc * 2]      = *(const f32x4*)(gp + kc * 32 + ks);
            gt[kc * 2 + 1]  = *(const f32x4*)(gp + kc * 32 + ks + 4);
            btv[kc * 2]     = *(const f32x4*)(bp + kc * 32 + ks);
            btv[kc * 2 + 1] = *(const f32x4*)(bp + kc * 32 + ks + 4);
        }
    }
    float bo[4];
    #pragma unroll
    for (int ot = 0; ot < 4; ++ot) bo[ot] = bias[g * 64 + ot * 16 + l15];

    // ---- 3) issue x tile-0/1 loads (youngest: waits above don't drain them) ----
    f32x4 buf[3][4];
    {
        const float* rowp0 = xg + (size_t)(rr0 + l15) * 64;
        buf[0][0] = *(const f32x4*)(rowp0 + ks);
        buf[0][1] = *(const f32x4*)(rowp0 + ks + 4);
        buf[0][2] = *(const f32x4*)(rowp0 + 32 + ks);
        buf[0][3] = *(const f32x4*)(rowp0 + 32 + ks + 4);
        const float* rowp1 = xg + (size_t)(rr0 + 16 + l15) * 64;
        buf[1][0] = *(const f32x4*)(rowp1 + ks);
        buf[1][1] = *(const f32x4*)(rowp1 + ks + 4);
        buf[1][2] = *(const f32x4*)(rowp1 + 32 + ks);
        buf[1][3] = *(const f32x4*)(rowp1 + 32 + ks + 4);
    }

    // ---- 4) convert W -> bfrag (waits retire W only; x still in flight) ----
    bf16x8 bfrag[4][2];
    #pragma unroll
    for (int ot = 0; ot < 4; ++ot) {
        #pragma unroll
        for (int kc = 0; kc < 2; ++kc) {
            bf16x8 f;
            #pragma unroll
            for (int j = 0; j < 4; ++j) {
                f[j]     = bf16_rne(wt0[ot][kc][j]);
                f[j + 4] = bf16_rne(wt1[ot][kc][j]);
            }
            bfrag[ot][kc] = f;
        }
    }

    // ---- 5) unpack gamma/beta (waits retire gamma/beta; x still in flight) ----
    float gk[16], bk[16];
    #pragma unroll
    for (int h = 0; h < 4; ++h) {
        #pragma unroll
        for (int j = 0; j < 4; ++j) {
            gk[(h >> 1) * 8 + (h & 1) * 4 + j] = gt[h][j];
            bk[(h >> 1) * 8 + (h & 1) * 4 + j] = btv[h][j];
        }
    }

    f32x4 vout[4][4];                   // [tile][ot] — all stores deferred

    #pragma unroll
    for (int t = 0; t < 4; ++t) {
        // 2-deep prefetch: tile t+2 while computing tile t (t+1 already in flight)
        if (t + 2 < 4) {
            const float* rowp = xg + (size_t)(rr0 + (t + 2) * 16 + l15) * 64;
            buf[(t + 2) % 3][0] = *(const f32x4*)(rowp + ks);
            buf[(t + 2) % 3][1] = *(const f32x4*)(rowp + ks + 4);
            buf[(t + 2) % 3][2] = *(const f32x4*)(rowp + 32 + ks);
            buf[(t + 2) % 3][3] = *(const f32x4*)(rowp + 32 + ks + 4);
        }
        const int tb = t % 3;

        // LN stats over the row (4 lanes share a row: xor 16, 32)
        float s = 0.f, s2 = 0.f;
        #pragma unroll
        for (int i = 0; i < 4; ++i) {
            #pragma unroll
            for (int j = 0; j < 4; ++j) {
                float v = buf[tb][i][j];
                s += v; s2 += v * v;
            }
        }
        s  += __shfl_xor(s, 16, 64);  s  += __shfl_xor(s, 32, 64);
        s2 += __shfl_xor(s2, 16, 64); s2 += __shfl_xor(s2, 32, 64);
        const float mu   = s * (1.0f / 64.0f);
        const float var  = s2 * (1.0f / 64.0f) - mu * mu;
        const float rstd = rsqrtf(var + 1e-6f);

        // normalize + affine -> A fragments (bf16)   [R1 numerics]
        bf16x8 a0, a1;
        #pragma unroll
        for (int j = 0; j < 8; ++j) {
            float c1 = rstd * gk[j];
            float v  = buf[tb][j >> 2][j & 3] * c1 + (bk[j] - mu * c1);
            a0[j] = bf16_rne(v);
        }
        #pragma unroll
        for (int j = 0; j < 8; ++j) {
            float c1 = rstd * gk[8 + j];
            float v  = buf[tb][2 + (j >> 2)][j & 3] * c1 + (bk[8 + j] - mu * c1);
            a1[j] = bf16_rne(v);
        }

        #pragma unroll
        for (int ot = 0; ot < 4; ++ot) {
            f32x4 acc = {0.f, 0.f, 0.f, 0.f};
            acc = __builtin_amdgcn_mfma_f32_16x16x32_bf16(a0, bfrag[ot][0], acc, 0, 0, 0);
            acc = __builtin_amdgcn_mfma_f32_16x16x32_bf16(a1, bfrag[ot][1], acc, 0, 0, 0);
            #pragma unroll
            for (int q = 0; q < 4; ++q) acc[q] += bo[ot];
            vout[t][ot] = acc;
        }
    }

    // ---- epilogue: per channel, its FULL 256 B span in 4 adjacent nt stores ----
    #pragma unroll
    for (int ot = 0; ot < 4; ++ot) {
        float* base = outg + (size_t)(ot * 16 + l15) * 32768 + rr0 + l4 * 4;
        #pragma unroll
        for (int t = 0; t < 4; ++t) {
            __builtin_nontemporal_store(vout[t][ot], (f32x4*)(base + t * 16));
        }
    }
}

extern "C" void kernel_launch(void* const* d_in, const int* in_sizes, int n_in,
                              void* d_out, int out_size, void* d_ws, size_t ws_size,
                              hipStream_t stream) {
    const float* x     = (const float*)d_in[0];
    const float* gamma = (const float*)d_in[1];
    const float* beta  = (const float*)d_in[2];
    const float* W     = (const float*)d_in[3];
    const float* b     = (const float*)d_in[4];
    float* out = (float*)d_out;

    dim3 grid(2048), block(256);
    hipLaunchKernelGGL(gln_mfma_kernel, grid, block, 0, stream, x, gamma, beta, W, b, out);
}